// Round 21
// baseline (105.250 us; speedup 1.0000x reference)
//
#include <hip/hip_runtime.h>
#include <cstdint>
#include <cstddef>

#define IN_F 4096
#define OUT_F 4096
#define NROWS 8192
#define PI_F 3.14159265358979323846f

// padded complex index (R19-verified): monotone/injective, bank-bijective
#define PD(a) ((a) + ((a) >> 4) + 3 * ((a) >> 7))
#define ROWSTR 2224   // PD(2047)=2219 < 2224

__device__ inline float2 cmul(float2 a, float2 b) {
    return make_float2(a.x * b.x - a.y * b.y, a.x * b.y + a.y * b.x);
}

// Twiddle tables (verified): tw[m]=e^{-i pi m/1024}; f3[k]=e^{-i pi k/8192};
// f23[k]=e^{-i 5 pi k/8192}
__global__ void twprep(float2* __restrict__ tw, float2* __restrict__ f3,
                       float2* __restrict__ f23) {
    const int i = blockIdx.x * 256 + threadIdx.x;   // 0..2047
    float s, c;
    if (i < 1024) {
        sincosf(-PI_F * (float)i / 1024.0f, &s, &c);
        tw[i] = make_float2(c, s);
    }
    sincosf(-PI_F * (float)i / 8192.0f, &s, &c);
    f3[i] = make_float2(c, s);
    sincosf(-PI_F * 5.0f * (float)i / 8192.0f, &s, &c);
    f23[i] = make_float2(c, s);
}

// Unit-twiddle radix-4 DFT core (verified R18/R19)
struct c4 { float2 z0, z1, z2, z3; };
__device__ __forceinline__ c4 r4unit(float2 x0, float2 x1, float2 x2, float2 x3) {
    const float2 E = make_float2(x0.x + x2.x, x0.y + x2.y);
    const float2 G = make_float2(x0.x - x2.x, x0.y - x2.y);
    const float2 F = make_float2(x1.x + x3.x, x1.y + x3.y);
    const float2 H = make_float2(x1.x - x3.x, x1.y - x3.y);
    c4 r;
    r.z0 = make_float2(E.x + F.x, E.y + F.y);
    r.z2 = make_float2(E.x - F.x, E.y - F.y);
    r.z1 = make_float2(G.x + H.y, G.y - H.x);   // G - iH
    r.z3 = make_float2(G.x - H.y, G.y + H.x);   // G + iH
    return r;
}

// wave-internal LDS ordering fence (R19-verified mechanism; rule #18)
#define WFENCE do { \
    asm volatile("s_waitcnt lgkmcnt(0)" ::: "memory"); \
    __builtin_amdgcn_sched_barrier(0); \
} while (0)

// In-place DIF radix-4 stage, wave-local: 8 butterflies/lane (b = q*64+lane).
// Math verified R18/R19.
template<int S>
__device__ __forceinline__ void dif4w(float2* __restrict__ V,
                                      const float2* __restrict__ TW, int lane) {
#pragma unroll
    for (int q = 0; q < 8; ++q) {
        const int b = q * 64 + lane;
        const int h = 512 >> (2 * S);
        const int i = b & (h - 1);
        const int base = ((b >> (9 - 2 * S)) << (11 - 2 * S)) + i;
        const float2 u1 = TW[i << (2 * S)];
        const float2 u2 = TW[i << (2 * S + 1)];
        const float2 u3 = cmul(u1, u2);
        const int p0 = PD(base), p1 = PD(base + h), p2 = PD(base + 2 * h),
                  p3 = PD(base + 3 * h);
        const c4 r = r4unit(V[p0], V[p1], V[p2], V[p3]);
        V[p0] = r.z0;
        V[p1] = cmul(u1, r.z1);
        V[p2] = cmul(u2, r.z2);
        V[p3] = cmul(u3, r.z3);
    }
}

// y[row] = orthonormal DST-II_4096(x[row]) + bias.
// ONE WAVE PER ROW, zero block barriers in steady state: each 64-lane wave
// runs the R18/R19-verified in-place DIF-4 FFT on its private LDS buffer,
// ordered only by wave-level lgkm fences. 4 rows/block; 2 blocks/CU; all
// 8 resident waves fully independent -> no convoy stalls.
__global__ __launch_bounds__(256, 2) void dst_row(const float* __restrict__ x,
                                                  const float* __restrict__ bias,
                                                  const float2* __restrict__ twg,
                                                  const float2* __restrict__ f3,
                                                  const float2* __restrict__ f23,
                                                  float* __restrict__ out) {
    __shared__ float2 VR[4][ROWSTR];   // 71.2 KB: one buffer per wave/row
    __shared__ float2 TW[1024];        // 8 KB shared twiddles
    const int t = threadIdx.x;
    const int lane = t & 63;
    const int w = t >> 6;
    const int row = blockIdx.x * 4 + w;
    const float* xr = x + (size_t)row * IN_F;
    float* yr = out + (size_t)row * OUT_F;
    float2* V = VR[w];

    // ---- startup: cooperative TW load; the ONLY block barrier ----
    TW[t] = twg[t];
    TW[t + 256] = twg[t + 256];
    TW[t + 512] = twg[t + 512];
    TW[t + 768] = twg[t + 768];
    __syncthreads();

    // ---- fused gather + DIF stage 0 (verified R18), 8 butterflies/lane ----
#pragma unroll
    for (int q = 0; q < 8; ++q) {
        const int m = q * 64 + lane;                  // 0..511
        const float4 v0 = *(const float4*)(xr + 4 * m);
        const float4 v1 = *(const float4*)(xr + 4 * (m + 512));
        const float4 v2 = *(const float4*)(xr + (4092 - 4 * m));
        const float4 v3 = *(const float4*)(xr + (2044 - 4 * m));
        const c4 r = r4unit(make_float2(v0.x, v0.z), make_float2(v1.x, v1.z),
                            make_float2(-v2.w, -v2.y), make_float2(-v3.w, -v3.y));
        const float2 w1 = TW[m];
        const float2 w2 = TW[2 * m];
        const float2 w3 = cmul(w1, w2);
        V[PD(m)]        = r.z0;
        V[PD(m + 512)]  = cmul(w1, r.z1);
        V[PD(m + 1024)] = cmul(w2, r.z2);
        V[PD(m + 1536)] = cmul(w3, r.z3);
    }
    WFENCE;

    // ---- in-place stages s=1..4, wave-local, fence-ordered ----
    dif4w<1>(V, TW, lane);
    WFENCE;
    dif4w<2>(V, TW, lane);
    WFENCE;
    dif4w<3>(V, TW, lane);
    WFENCE;
    dif4w<4>(V, TW, lane);
    WFENCE;
    // Z[k] = V[P(k)] +/- V[P(k)+1]  (+ iff k<1024), P = base-4 digit-reversal

    // ---- untangle + DST map (verified R18/R19), 32 k-slots/lane ----
    const float amp1 = 2.0f * rsqrtf(8192.0f);
    const float amp0 = 2.0f * rsqrtf(16384.0f);
#pragma unroll 4
    for (int q = 0; q < 32; ++q) {
        const int k = q * 64 + lane;                  // 0..2047
        const int P = ((k & 3) << 9) | (((k >> 2) & 3) << 7) | (((k >> 4) & 3) << 5)
                    | (((k >> 6) & 3) << 3) | (((k >> 8) & 3) << 1);
        const float2 a = V[PD(P)];
        const float2 b = V[PD(P) + 1];    // PD(P+1)==PD(P)+1 for even P
        const float2 z = (k < 1024) ? make_float2(a.x + b.x, a.y + b.y)
                                    : make_float2(a.x - b.x, a.y - b.y);
        const int kc = (2048 - k) & 2047;
        const int Pc = ((kc & 3) << 9) | (((kc >> 2) & 3) << 7) | (((kc >> 4) & 3) << 5)
                     | (((kc >> 6) & 3) << 3) | (((kc >> 8) & 3) << 1);
        const float2 ac = V[PD(Pc)];
        const float2 bc = V[PD(Pc) + 1];
        const float2 zc = (kc < 1024) ? make_float2(ac.x + bc.x, ac.y + bc.y)
                                      : make_float2(ac.x - bc.x, ac.y - bc.y);
        const float Arr = 0.5f * (z.x + zc.x), Aii = 0.5f * (z.y - zc.y);
        const float Brr = 0.5f * (z.y + zc.y), Bii = 0.5f * (zc.x - z.x);
        const float2 e3 = f3[k];
        const float2 eA = f23[k];
        const float Wr = Arr * e3.x - Aii * e3.y + Brr * eA.x - Bii * eA.y;
        const float Wi = Arr * e3.y + Aii * e3.x + Brr * eA.y + Bii * eA.x;
        const int o1 = 4095 - k;
        yr[o1] = amp1 * Wr + bias[o1];
        if (k > 0) {
            const int o2 = k - 1;
            const float amp = (o2 == 0) ? amp0 : amp1;
            yr[o2] = amp * (-Wi) + bias[o2];
        } else {
            const float C2048 = (z.x - z.y) * 0.70710678118654752f;
            yr[2047] = amp1 * C2048 + bias[2047];
        }
    }
}

// Fallback (round-11 kernel, HW-verified): used only if ws is too small for tables.
__global__ __launch_bounds__(256) void dst_row_fb(const float* __restrict__ x,
                                                  const float* __restrict__ bias,
                                                  float* __restrict__ out) {
    __shared__ float Ar[2048], Ai[2048], Br[2048], Bi[2048];
    const int t = threadIdx.x;
    const int row = blockIdx.x;
    const float* xr = x + (size_t)row * IN_F;
    float* yr = out + (size_t)row * OUT_F;
#pragma unroll
    for (int q = 0; q < 8; ++q) {
        const int m = t + q * 256;
        float re, im;
        if (m < 1024) {
            const float4 v = *(const float4*)(xr + 4 * m);
            re = v.x; im = v.z;
        } else {
            const float4 v = *(const float4*)(xr + (8188 - 4 * m));
            re = -v.w; im = -v.y;
        }
        Ar[m] = re; Ai[m] = im;
    }
    __syncthreads();
    float *sr = Ar, *si = Ai, *dr = Br, *di = Bi;
    for (int s = 0; s < 11; ++s) {
        const int mm = 1024 >> s;
#pragma unroll
        for (int q = 0; q < 4; ++q) {
            const int b = t + q * 256;
            const int j = b >> (10 - s);
            const int i = b & (mm - 1);
            const int i0 = i + j * 2 * mm;
            const float ar = sr[i0], aim = si[i0];
            const float cr = sr[i0 + mm], ci = si[i0 + mm];
            float sw, cw;
            __sincosf(-PI_F * (float)j / (float)(1 << s), &sw, &cw);
            const float wr = cr * cw - ci * sw;
            const float wi = cr * sw + ci * cw;
            const int o0 = i + j * mm;
            dr[o0] = ar + wr;        di[o0] = aim + wi;
            dr[o0 + 1024] = ar - wr; di[o0 + 1024] = aim - wi;
        }
        __syncthreads();
        float* tp;
        tp = sr; sr = dr; dr = tp;
        tp = si; si = di; di = tp;
    }
    const float amp1 = 2.0f * rsqrtf(8192.0f);
    const float amp0 = 2.0f * rsqrtf(16384.0f);
#pragma unroll
    for (int q = 0; q < 8; ++q) {
        const int k = t + q * 256;
        const float zr = sr[k], zi = si[k];
        const int kc = (2048 - k) & 2047;
        const float cr = sr[kc], ci = si[kc];
        const float Arr = 0.5f * (zr + cr), Aii = 0.5f * (zi - ci);
        const float Brr = 0.5f * (zi + ci), Bii = 0.5f * (cr - zr);
        float s2, c2;
        __sincosf(-PI_F * (float)k / 2048.0f, &s2, &c2);
        const float Vr = Arr + Brr * c2 - Bii * s2;
        const float Vi = Aii + Brr * s2 + Bii * c2;
        float s3, c3;
        __sincosf(-PI_F * (float)k / 8192.0f, &s3, &c3);
        const float Wr = Vr * c3 - Vi * s3;
        const float Wi = Vr * s3 + Vi * c3;
        const int o1 = 4095 - k;
        yr[o1] = amp1 * Wr + bias[o1];
        if (k > 0) {
            const int o2 = k - 1;
            const float amp = (o2 == 0) ? amp0 : amp1;
            yr[o2] = amp * (-Wi) + bias[o2];
        } else {
            const float C2048 = (zr - zi) * 0.70710678118654752f;
            yr[2047] = amp1 * C2048 + bias[2047];
        }
    }
}

extern "C" void kernel_launch(void* const* d_in, const int* in_sizes, int n_in,
                              void* d_out, int out_size, void* d_ws, size_t ws_size,
                              hipStream_t stream) {
    const float* x    = (const float*)d_in[0];
    const float* bias = (const float*)d_in[2];
    float* out = (float*)d_out;

    if (ws_size >= 40960) {
        float2* tw  = (float2*)d_ws;                       // 1024 (8 KB)
        float2* f3  = (float2*)((char*)d_ws + 8192);       // 2048 (16 KB)
        float2* f23 = (float2*)((char*)d_ws + 24576);      // 2048 (16 KB)
        twprep<<<8, 256, 0, stream>>>(tw, f3, f23);
        dst_row<<<NROWS / 4, 256, 0, stream>>>(x, bias, tw, f3, f23, out);
    } else {
        dst_row_fb<<<NROWS, 256, 0, stream>>>(x, bias, out);
    }
}